// Round 5
// baseline (308.628 us; speedup 1.0000x reference)
//
#include <hip/hip_runtime.h>

typedef _Float16 f16x8 __attribute__((ext_vector_type(8)));
typedef float f32x4 __attribute__((ext_vector_type(4)));

#define NMAT3 (3 * 768 * 64)
#define NROWS 32768   // 8 * 4096

// ---------------- Kernel 0: W transpose/convert ----------------
__global__ __launch_bounds__(256) void prep_w(const float* __restrict__ Wq,
                                              const float* __restrict__ Wk,
                                              const float* __restrict__ Wv,
                                              _Float16* __restrict__ wt) {
    int tid = blockIdx.x * 256 + threadIdx.x;
    if (tid >= NMAT3) return;
    int m = tid / (768 * 64);
    int rem = tid - m * (768 * 64);
    int k = rem >> 6;
    int n = rem & 63;
    const float* W = (m == 0) ? Wq : (m == 1) ? Wk : Wv;
    float v = W[k * 64 + n];
    wt[(m * 64 + n) * 768 + k] = (_Float16)v;
}

// ---------------- Kernel 1: QKV projection, register-prefetched ----------
// 4 waves/block, wave = 16 rows x 192 cols. 1-deep prefetch of A (x, fp32)
// and 12 B-fragments (wt, f16, L2-resident) hides load latency under MFMA.
__global__ __launch_bounds__(256, 2) void qkv_proj(const float* __restrict__ x,
                                                   const _Float16* __restrict__ wt,
                                                   const float* __restrict__ bq,
                                                   const float* __restrict__ bk,
                                                   const float* __restrict__ bv,
                                                   _Float16* __restrict__ qo,
                                                   _Float16* __restrict__ ko,
                                                   _Float16* __restrict__ vo) {
    const int t = threadIdx.x;
    const int lane = t & 63;
    const int w = t >> 6;
    const int l15 = lane & 15;
    const int lg = lane >> 4;
    const int row0 = blockIdx.x * 64 + w * 16;

    f32x4 acc[12];
#pragma unroll
    for (int i = 0; i < 12; i++) acc[i] = (f32x4)(0.0f);

    const float* xrow = x + (long)(row0 + l15) * 768 + lg * 8;
    const _Float16* wbase = wt + (long)l15 * 768 + lg * 8;

    // prologue: load K-step 0
    float4 a0 = *(const float4*)(xrow);
    float4 a1 = *(const float4*)(xrow + 4);
    f16x8 bf[12];
#pragma unroll
    for (int nf = 0; nf < 12; nf++) bf[nf] = *(const f16x8*)(wbase + nf * 12288);

    for (int k0 = 0; k0 < 736; k0 += 32) {
        // prefetch K-step k0+32
        float4 a0n = *(const float4*)(xrow + k0 + 32);
        float4 a1n = *(const float4*)(xrow + k0 + 36);
        f16x8 bfn[12];
#pragma unroll
        for (int nf = 0; nf < 12; nf++)
            bfn[nf] = *(const f16x8*)(wbase + nf * 12288 + k0 + 32);

        // compute current
        f16x8 af;
        af[0] = (_Float16)a0.x; af[1] = (_Float16)a0.y;
        af[2] = (_Float16)a0.z; af[3] = (_Float16)a0.w;
        af[4] = (_Float16)a1.x; af[5] = (_Float16)a1.y;
        af[6] = (_Float16)a1.z; af[7] = (_Float16)a1.w;
#pragma unroll
        for (int nf = 0; nf < 12; nf++)
            acc[nf] = __builtin_amdgcn_mfma_f32_16x16x32_f16(af, bf[nf], acc[nf], 0, 0, 0);

        a0 = a0n; a1 = a1n;
#pragma unroll
        for (int nf = 0; nf < 12; nf++) bf[nf] = bfn[nf];
    }
    {   // tail K-step (k0 = 736)
        f16x8 af;
        af[0] = (_Float16)a0.x; af[1] = (_Float16)a0.y;
        af[2] = (_Float16)a0.z; af[3] = (_Float16)a0.w;
        af[4] = (_Float16)a1.x; af[5] = (_Float16)a1.y;
        af[6] = (_Float16)a1.z; af[7] = (_Float16)a1.w;
#pragma unroll
        for (int nf = 0; nf < 12; nf++)
            acc[nf] = __builtin_amdgcn_mfma_f32_16x16x32_f16(af, bf[nf], acc[nf], 0, 0, 0);
    }

    _Float16* outs[3] = {qo, ko, vo};
    const float* biases[3] = {bq, bk, bv};
#pragma unroll
    for (int nf = 0; nf < 12; nf++) {
        const int mat = nf >> 2;
        const int dcol = (nf & 3) * 16 + l15;
        const float bias = biases[mat][dcol];
#pragma unroll
        for (int r = 0; r < 4; r++) {
            int grow = row0 + lg * 4 + r;
            outs[mat][(long)grow * 64 + dcol] = (_Float16)(acc[nf][r] + bias);
        }
    }
}

// ---------------- Kernel 2: causal flash attention, s-split 2-way ---------
// 1024 blocks = 8 batches x 64 qtiles x 2 halves. Each half writes
// unnormalized O + per-row (m, l). Batch pinned to XCD via bid&7.
__global__ __launch_bounds__(256) void attn(const _Float16* __restrict__ qg,
                                            const _Float16* __restrict__ kg,
                                            const _Float16* __restrict__ vg,
                                            float* __restrict__ o0,
                                            float* __restrict__ o1,
                                            float2* __restrict__ stats) {
    __shared__ alignas(16) _Float16 Ks[2][64][72];
    __shared__ alignas(16) _Float16 Vs[2][64][72];   // [d][s] transposed
    __shared__ alignas(16) _Float16 Ps[4][16][72];

    const int t = threadIdx.x;
    const int lane = t & 63;
    const int w = t >> 6;
    const int l15 = lane & 15;
    const int lg = lane >> 4;

    const int bid = blockIdx.x;
    const int b = bid & 7;            // batch -> XCD pin (K/V L2-resident)
    const int rest = bid >> 3;        // 0..127
    const int h = rest & 1;
    const int tq = rest >> 1;         // 0..63
    int qt;                           // balance map: co-resident blocks sum ~const
    if      (tq < 16) qt = tq;
    else if (tq < 32) qt = 79 - tq;
    else if (tq < 48) qt = tq - 16;
    else              qt = 95 - tq;

    const int qbase = qt * 64;
    const long rowb = (long)b * 4096;
    const int ntiles = qt + 1;
    const int n0 = (ntiles + 1) >> 1;
    const int t0 = h ? n0 : 0;
    const int cnt = h ? (ntiles - n0) : n0;

    float mrow[4], lrow[4];
#pragma unroll
    for (int r = 0; r < 4; r++) { mrow[r] = -1e30f; lrow[r] = 0.0f; }

    if (cnt > 0) {
        const int sK = lane;
        const int dK = w * 16;

        f16x8 qf[2];
        {
            const _Float16* qptr = qg + (rowb + qbase + 16 * w + l15) * 64 + lg * 8;
            qf[0] = *(const f16x8*)(qptr);
            qf[1] = *(const f16x8*)(qptr + 32);
        }

        f32x4 oacc[4];
#pragma unroll
        for (int i = 0; i < 4; i++) oacc[i] = (f32x4)(0.0f);

        const float kscale = 0.125f * 1.44269504088896340736f;

        f16x8 krg0, krg1, vrg0, vrg1;
        {   // prologue: tile t0 -> buffer 0
            const long nb = rowb + (long)t0 * 64 + sK;
            const _Float16* ksrc = kg + nb * 64 + dK;
            krg0 = *(const f16x8*)(ksrc);
            krg1 = *(const f16x8*)(ksrc + 8);
            const _Float16* vsrc = vg + nb * 64 + dK;
            vrg0 = *(const f16x8*)(vsrc);
            vrg1 = *(const f16x8*)(vsrc + 8);
            *(f16x8*)(&Ks[0][sK][dK]) = krg0;
            *(f16x8*)(&Ks[0][sK][dK + 8]) = krg1;
#pragma unroll
            for (int j = 0; j < 8; j++) Vs[0][dK + j][sK] = vrg0[j];
#pragma unroll
            for (int j = 0; j < 8; j++) Vs[0][dK + 8 + j][sK] = vrg1[j];
        }

        for (int i = 0; i < cnt; i++) {
            const int st = t0 + i;
            const int cur = i & 1;
            const int sbase = st * 64;
            __syncthreads();

            if (i + 1 < cnt) {   // issue next tile's global loads early
                const long nb = rowb + sbase + 64 + sK;
                const _Float16* ksrc = kg + nb * 64 + dK;
                krg0 = *(const f16x8*)(ksrc);
                krg1 = *(const f16x8*)(ksrc + 8);
                const _Float16* vsrc = vg + nb * 64 + dK;
                vrg0 = *(const f16x8*)(vsrc);
                vrg1 = *(const f16x8*)(vsrc + 8);
            }

            // S = Q K^T
            f32x4 sacc[4];
            __builtin_amdgcn_s_setprio(1);
#pragma unroll
            for (int cf = 0; cf < 4; cf++) {
                sacc[cf] = (f32x4)(0.0f);
#pragma unroll
                for (int kk = 0; kk < 2; kk++) {
                    f16x8 bfrag = *(const f16x8*)(&Ks[cur][16 * cf + l15][kk * 32 + lg * 8]);
                    sacc[cf] = __builtin_amdgcn_mfma_f32_16x16x32_f16(qf[kk], bfrag, sacc[cf], 0, 0, 0);
                }
            }
            __builtin_amdgcn_s_setprio(0);

            const bool diag = (st == qt);
            float sv[4][4];
#pragma unroll
            for (int cf = 0; cf < 4; cf++) {
                int scol = sbase + 16 * cf + l15;
#pragma unroll
                for (int r = 0; r < 4; r++) {
                    float val = sacc[cf][r] * kscale;
                    if (diag) {
                        int qrow = qbase + 16 * w + lg * 4 + r;
                        if (scol > qrow) val = -1e30f;
                    }
                    sv[cf][r] = val;
                }
            }

            float fr[4];
#pragma unroll
            for (int r = 0; r < 4; r++) {
                float mx = fmaxf(fmaxf(sv[0][r], sv[1][r]), fmaxf(sv[2][r], sv[3][r]));
                mx = fmaxf(mx, __shfl_xor(mx, 1, 64));
                mx = fmaxf(mx, __shfl_xor(mx, 2, 64));
                mx = fmaxf(mx, __shfl_xor(mx, 4, 64));
                mx = fmaxf(mx, __shfl_xor(mx, 8, 64));
                float mnew = fmaxf(mrow[r], mx);
                fr[r] = __builtin_amdgcn_exp2f(mrow[r] - mnew);
                mrow[r] = mnew;
                float psum = 0.0f;
#pragma unroll
                for (int cf = 0; cf < 4; cf++) {
                    float p = __builtin_amdgcn_exp2f(sv[cf][r] - mnew);
                    sv[cf][r] = p;
                    psum += p;
                }
                psum += __shfl_xor(psum, 1, 64);
                psum += __shfl_xor(psum, 2, 64);
                psum += __shfl_xor(psum, 4, 64);
                psum += __shfl_xor(psum, 8, 64);
                lrow[r] = lrow[r] * fr[r] + psum;
            }
#pragma unroll
            for (int df = 0; df < 4; df++)
#pragma unroll
                for (int r = 0; r < 4; r++) oacc[df][r] *= fr[r];

            // P -> per-wave LDS (D-frag -> A-frag re-layout)
#pragma unroll
            for (int cf = 0; cf < 4; cf++)
#pragma unroll
                for (int r = 0; r < 4; r++)
                    Ps[w][lg * 4 + r][16 * cf + l15] = (_Float16)sv[cf][r];

            // O += P V
            __builtin_amdgcn_s_setprio(1);
#pragma unroll
            for (int kk = 0; kk < 2; kk++) {
                f16x8 pfrag = *(const f16x8*)(&Ps[w][l15][kk * 32 + lg * 8]);
#pragma unroll
                for (int df = 0; df < 4; df++) {
                    f16x8 vfrag = *(const f16x8*)(&Vs[cur][16 * df + l15][kk * 32 + lg * 8]);
                    oacc[df] = __builtin_amdgcn_mfma_f32_16x16x32_f16(pfrag, vfrag, oacc[df], 0, 0, 0);
                }
            }
            __builtin_amdgcn_s_setprio(0);

            if (i + 1 < cnt) {   // stage next tile into the other buffer
                const int nxt = cur ^ 1;
                *(f16x8*)(&Ks[nxt][sK][dK]) = krg0;
                *(f16x8*)(&Ks[nxt][sK][dK + 8]) = krg1;
#pragma unroll
                for (int j = 0; j < 8; j++) Vs[nxt][dK + j][sK] = vrg0[j];
#pragma unroll
                for (int j = 0; j < 8; j++) Vs[nxt][dK + 8 + j][sK] = vrg1[j];
            }
        }

        // write unnormalized partial O
        float* op = h ? o1 : o0;
#pragma unroll
        for (int df = 0; df < 4; df++)
#pragma unroll
            for (int r = 0; r < 4; r++) {
                int qrow = qbase + 16 * w + lg * 4 + r;
                op[(rowb + qrow) * 64 + 16 * df + l15] = oacc[df][r];
            }
    }

    // per-row stats (m, l) — lane-group leader writes
    if (l15 == 0) {
#pragma unroll
        for (int r = 0; r < 4; r++) {
            long row = rowb + qbase + 16 * w + lg * 4 + r;
            stats[(long)h * NROWS + row] = make_float2(mrow[r], lrow[r]);
        }
    }
}

// ---------------- Kernel 3: merge the two halves ----------------
__global__ __launch_bounds__(256) void merge(float* __restrict__ o0,
                                             const float* __restrict__ o1,
                                             const float2* __restrict__ stats) {
    int idx = blockIdx.x * 256 + threadIdx.x;   // 524288 total, float4 each
    int row = idx >> 4;
    int c = (idx & 15) << 2;
    float2 s0 = stats[row];
    float2 s1 = stats[NROWS + row];
    float m = fmaxf(s0.x, s1.x);
    float w0 = __builtin_amdgcn_exp2f(s0.x - m);
    float w1 = __builtin_amdgcn_exp2f(s1.x - m);
    float inv = 1.0f / (w0 * s0.y + w1 * s1.y);
    const float4 a = *(const float4*)(o0 + (long)row * 64 + c);
    const float4 bb = *(const float4*)(o1 + (long)row * 64 + c);
    float4 o;
    o.x = (w0 * a.x + w1 * bb.x) * inv;
    o.y = (w0 * a.y + w1 * bb.y) * inv;
    o.z = (w0 * a.z + w1 * bb.z) * inv;
    o.w = (w0 * a.w + w1 * bb.w) * inv;
    *(float4*)(o0 + (long)row * 64 + c) = o;
}

extern "C" void kernel_launch(void* const* d_in, const int* in_sizes, int n_in,
                              void* d_out, int out_size, void* d_ws, size_t ws_size,
                              hipStream_t stream) {
    const float* x  = (const float*)d_in[0];
    const float* Wq = (const float*)d_in[1];
    const float* bq = (const float*)d_in[2];
    const float* Wk = (const float*)d_in[3];
    const float* bk = (const float*)d_in[4];
    const float* Wv = (const float*)d_in[5];
    const float* bv = (const float*)d_in[6];
    float* out = (float*)d_out;

    char* wsb = (char*)d_ws;
    _Float16* wt = (_Float16*)wsb;                          // 294912 B
    _Float16* qb = (_Float16*)(wsb + 294912);               // 4 MB each
    _Float16* kb = qb + 2097152;
    _Float16* vb = kb + 2097152;
    float*  o1    = (float*)(wsb + 12877824);               // 8388608 B
    float2* stats = (float2*)(wsb + 21266432);              // 524288 B

    prep_w<<<576, 256, 0, stream>>>(Wq, Wk, Wv, wt);
    qkv_proj<<<512, 256, 0, stream>>>(x, wt, bq, bk, bv, qb, kb, vb);
    attn<<<1024, 256, 0, stream>>>(qb, kb, vb, out, o1, stats);
    merge<<<2048, 256, 0, stream>>>(out, o1, stats);
}

// Round 6
// 304.558 us; speedup vs baseline: 1.0134x; 1.0134x over previous
//
#include <hip/hip_runtime.h>

typedef _Float16 f16x8 __attribute__((ext_vector_type(8)));
typedef _Float16 f16x4 __attribute__((ext_vector_type(4)));
typedef float f32x4 __attribute__((ext_vector_type(4)));

#define NMAT3 (3 * 768 * 64)
#define NROWS 32768   // 8 * 4096

// ---------------- Kernel 0: W transpose/convert ----------------
// Wt layout: [n = mat*64 + d][k], f16.
__global__ __launch_bounds__(256) void prep_w(const float* __restrict__ Wq,
                                              const float* __restrict__ Wk,
                                              const float* __restrict__ Wv,
                                              _Float16* __restrict__ wt) {
    int tid = blockIdx.x * 256 + threadIdx.x;
    if (tid >= NMAT3) return;
    int m = tid / (768 * 64);
    int rem = tid - m * (768 * 64);
    int k = rem >> 6;
    int n = rem & 63;
    const float* W = (m == 0) ? Wq : (m == 1) ? Wk : Wv;
    float v = W[k * 64 + n];
    wt[(m * 64 + n) * 768 + k] = (_Float16)v;
}

// ---------------- Kernel 1: QKV projection, occupancy-first ----------
// 1536 blocks (512 row-tiles x 3 matrices), 4 waves/block.
// Wave = 16 rows x 64 cols of ONE matrix: acc=4 frags, low VGPR ->
// 6 blocks/CU = 24 waves/CU; TLP hides load latency. No LDS, no barriers.
__global__ __launch_bounds__(256) void qkv_proj(const float* __restrict__ x,
                                                const _Float16* __restrict__ wt,
                                                const float* __restrict__ bq,
                                                const float* __restrict__ bk,
                                                const float* __restrict__ bv,
                                                _Float16* __restrict__ qo,
                                                _Float16* __restrict__ ko,
                                                _Float16* __restrict__ vo) {
    const int t = threadIdx.x;
    const int lane = t & 63;
    const int w = t >> 6;
    const int l15 = lane & 15;
    const int lg = lane >> 4;

    const int bid = blockIdx.x;
    const int mat = bid % 3;
    const int rt  = bid / 3;
    const int row0 = rt * 64 + w * 16;

    f32x4 acc[4];
#pragma unroll
    for (int i = 0; i < 4; i++) acc[i] = (f32x4)(0.0f);

    const float* xrow = x + (long)(row0 + l15) * 768 + lg * 8;
    const _Float16* wb = wt + (long)(mat * 64 + l15) * 768 + lg * 8;

    for (int k0 = 0; k0 < 768; k0 += 32) {
        float4 a0 = *(const float4*)(xrow + k0);
        float4 a1 = *(const float4*)(xrow + k0 + 4);
        f16x8 b0 = *(const f16x8*)(wb + k0);
        f16x8 b1 = *(const f16x8*)(wb + k0 + 12288);
        f16x8 b2 = *(const f16x8*)(wb + k0 + 24576);
        f16x8 b3 = *(const f16x8*)(wb + k0 + 36864);
        f16x8 af;
        af[0] = (_Float16)a0.x; af[1] = (_Float16)a0.y;
        af[2] = (_Float16)a0.z; af[3] = (_Float16)a0.w;
        af[4] = (_Float16)a1.x; af[5] = (_Float16)a1.y;
        af[6] = (_Float16)a1.z; af[7] = (_Float16)a1.w;
        acc[0] = __builtin_amdgcn_mfma_f32_16x16x32_f16(af, b0, acc[0], 0, 0, 0);
        acc[1] = __builtin_amdgcn_mfma_f32_16x16x32_f16(af, b1, acc[1], 0, 0, 0);
        acc[2] = __builtin_amdgcn_mfma_f32_16x16x32_f16(af, b2, acc[2], 0, 0, 0);
        acc[3] = __builtin_amdgcn_mfma_f32_16x16x32_f16(af, b3, acc[3], 0, 0, 0);
    }

    const float* bias_p = (mat == 0) ? bq : (mat == 1) ? bk : bv;
    _Float16* outp = (mat == 0) ? qo : (mat == 1) ? ko : vo;
#pragma unroll
    for (int nf = 0; nf < 4; nf++) {
        const int dcol = nf * 16 + l15;
        const float bias = bias_p[dcol];
#pragma unroll
        for (int r = 0; r < 4; r++) {
            int grow = row0 + lg * 4 + r;
            outp[(long)grow * 64 + dcol] = (_Float16)(acc[nf][r] + bias);
        }
    }
}

// ---------------- Kernel 2: causal flash attention, s-split 4-way ---------
// 2048 blocks = 8 batches x 64 qtiles x 4 splits, LPT (heavy qt first).
// Single-buffered K/V (LDS 27.6KB -> 5 blocks/CU = 20 waves/CU) with T14
// reg-staging: loads for tile i+1 issued after barrier1, written after
// barrier2. Split 0 writes f32 to out; splits 1-3 write f16 partials.
__global__ __launch_bounds__(256) void attn(const _Float16* __restrict__ qg,
                                            const _Float16* __restrict__ kg,
                                            const _Float16* __restrict__ vg,
                                            float* __restrict__ o0,
                                            _Float16* __restrict__ op,
                                            float2* __restrict__ stats) {
    __shared__ alignas(16) _Float16 Ks[64][72];
    __shared__ alignas(16) _Float16 Vs[64][72];     // [d][s] transposed
    __shared__ alignas(16) _Float16 Ps[4][16][72];

    const int t = threadIdx.x;
    const int lane = t & 63;
    const int w = t >> 6;
    const int l15 = lane & 15;
    const int lg = lane >> 4;

    const int bid = blockIdx.x;
    const int b = bid & 7;           // batch -> XCD pin
    const int rest = bid >> 3;       // 0..255
    const int h = rest & 3;          // split id
    const int tq = rest >> 2;        // 0..63
    const int qt = 63 - tq;          // heavy tiles dispatched first (LPT)

    const int qbase = qt * 64;
    const long rowb = (long)b * 4096;
    const int ntiles = qt + 1;
    const int base = ntiles >> 2;
    const int rem = ntiles & 3;
    const int cnt = base + (h < rem ? 1 : 0);
    const int t0 = h * base + (h < rem ? h : rem);

    float mrow[4], lrow[4];
#pragma unroll
    for (int r = 0; r < 4; r++) { mrow[r] = -1e30f; lrow[r] = 0.0f; }

    if (cnt > 0) {
        const int sK = lane;
        const int dK = w * 16;

        f16x8 qf[2];
        {
            const _Float16* qptr = qg + (rowb + qbase + 16 * w + l15) * 64 + lg * 8;
            qf[0] = *(const f16x8*)(qptr);
            qf[1] = *(const f16x8*)(qptr + 32);
        }

        f32x4 oacc[4];
#pragma unroll
        for (int i = 0; i < 4; i++) oacc[i] = (f32x4)(0.0f);

        const float kscale = 0.125f * 1.44269504088896340736f;

        f16x8 krg0, krg1, vrg0, vrg1;
        {   // prologue: tile t0 -> LDS
            const long nb = rowb + (long)t0 * 64 + sK;
            const _Float16* ksrc = kg + nb * 64 + dK;
            krg0 = *(const f16x8*)(ksrc);
            krg1 = *(const f16x8*)(ksrc + 8);
            const _Float16* vsrc = vg + nb * 64 + dK;
            vrg0 = *(const f16x8*)(vsrc);
            vrg1 = *(const f16x8*)(vsrc + 8);
            *(f16x8*)(&Ks[sK][dK]) = krg0;
            *(f16x8*)(&Ks[sK][dK + 8]) = krg1;
#pragma unroll
            for (int j = 0; j < 8; j++) Vs[dK + j][sK] = vrg0[j];
#pragma unroll
            for (int j = 0; j < 8; j++) Vs[dK + 8 + j][sK] = vrg1[j];
        }

        for (int i = 0; i < cnt; i++) {
            const int st = t0 + i;
            const int sbase = st * 64;
            __syncthreads();   // K/V tile i in LDS

            if (i + 1 < cnt) {   // T14: issue tile i+1 loads now, write later
                const long nb = rowb + sbase + 64 + sK;
                const _Float16* ksrc = kg + nb * 64 + dK;
                krg0 = *(const f16x8*)(ksrc);
                krg1 = *(const f16x8*)(ksrc + 8);
                const _Float16* vsrc = vg + nb * 64 + dK;
                vrg0 = *(const f16x8*)(vsrc);
                vrg1 = *(const f16x8*)(vsrc + 8);
            }

            // S = Q K^T
            f32x4 sacc[4];
            __builtin_amdgcn_s_setprio(1);
#pragma unroll
            for (int cf = 0; cf < 4; cf++) {
                sacc[cf] = (f32x4)(0.0f);
#pragma unroll
                for (int kk = 0; kk < 2; kk++) {
                    f16x8 bfrag = *(const f16x8*)(&Ks[16 * cf + l15][kk * 32 + lg * 8]);
                    sacc[cf] = __builtin_amdgcn_mfma_f32_16x16x32_f16(qf[kk], bfrag, sacc[cf], 0, 0, 0);
                }
            }
            __builtin_amdgcn_s_setprio(0);

            const bool diag = (st == qt);
            float sv[4][4];
#pragma unroll
            for (int cf = 0; cf < 4; cf++) {
                int scol = sbase + 16 * cf + l15;
#pragma unroll
                for (int r = 0; r < 4; r++) {
                    float val = sacc[cf][r] * kscale;
                    if (diag) {
                        int qrow = qbase + 16 * w + lg * 4 + r;
                        if (scol > qrow) val = -1e30f;
                    }
                    sv[cf][r] = val;
                }
            }

            float fr[4];
#pragma unroll
            for (int r = 0; r < 4; r++) {
                float mx = fmaxf(fmaxf(sv[0][r], sv[1][r]), fmaxf(sv[2][r], sv[3][r]));
                mx = fmaxf(mx, __shfl_xor(mx, 1, 64));
                mx = fmaxf(mx, __shfl_xor(mx, 2, 64));
                mx = fmaxf(mx, __shfl_xor(mx, 4, 64));
                mx = fmaxf(mx, __shfl_xor(mx, 8, 64));
                float mnew = fmaxf(mrow[r], mx);
                fr[r] = __builtin_amdgcn_exp2f(mrow[r] - mnew);
                mrow[r] = mnew;
                float psum = 0.0f;
#pragma unroll
                for (int cf = 0; cf < 4; cf++) {
                    float p = __builtin_amdgcn_exp2f(sv[cf][r] - mnew);
                    sv[cf][r] = p;
                    psum += p;
                }
                psum += __shfl_xor(psum, 1, 64);
                psum += __shfl_xor(psum, 2, 64);
                psum += __shfl_xor(psum, 4, 64);
                psum += __shfl_xor(psum, 8, 64);
                lrow[r] = lrow[r] * fr[r] + psum;
            }
#pragma unroll
            for (int df = 0; df < 4; df++)
#pragma unroll
                for (int r = 0; r < 4; r++) oacc[df][r] *= fr[r];

            // P -> per-wave LDS (D-frag -> A-frag re-layout)
#pragma unroll
            for (int cf = 0; cf < 4; cf++)
#pragma unroll
                for (int r = 0; r < 4; r++)
                    Ps[w][lg * 4 + r][16 * cf + l15] = (_Float16)sv[cf][r];

            // O += P V
            __builtin_amdgcn_s_setprio(1);
#pragma unroll
            for (int kk = 0; kk < 2; kk++) {
                f16x8 pfrag = *(const f16x8*)(&Ps[w][l15][kk * 32 + lg * 8]);
#pragma unroll
                for (int df = 0; df < 4; df++) {
                    f16x8 vfrag = *(const f16x8*)(&Vs[16 * df + l15][kk * 32 + lg * 8]);
                    oacc[df] = __builtin_amdgcn_mfma_f32_16x16x32_f16(pfrag, vfrag, oacc[df], 0, 0, 0);
                }
            }
            __builtin_amdgcn_s_setprio(0);

            __syncthreads();   // all reads of K/V done
            if (i + 1 < cnt) { // write the prefetched tile
                *(f16x8*)(&Ks[sK][dK]) = krg0;
                *(f16x8*)(&Ks[sK][dK + 8]) = krg1;
#pragma unroll
                for (int j = 0; j < 8; j++) Vs[dK + j][sK] = vrg0[j];
#pragma unroll
                for (int j = 0; j < 8; j++) Vs[dK + 8 + j][sK] = vrg1[j];
            }
        }

        // write unnormalized partial O
        if (h == 0) {
#pragma unroll
            for (int df = 0; df < 4; df++)
#pragma unroll
                for (int r = 0; r < 4; r++) {
                    int qrow = qbase + 16 * w + lg * 4 + r;
                    o0[(rowb + qrow) * 64 + 16 * df + l15] = oacc[df][r];
                }
        } else {
            _Float16* opart = op + (long)(h - 1) * 2097152;
#pragma unroll
            for (int df = 0; df < 4; df++)
#pragma unroll
                for (int r = 0; r < 4; r++) {
                    int qrow = qbase + 16 * w + lg * 4 + r;
                    opart[(rowb + qrow) * 64 + 16 * df + l15] = (_Float16)oacc[df][r];
                }
        }
    }

    // per-row stats (m, l)
    if (l15 == 0) {
#pragma unroll
        for (int r = 0; r < 4; r++) {
            long row = rowb + qbase + 16 * w + lg * 4 + r;
            stats[(long)h * NROWS + row] = make_float2(mrow[r], lrow[r]);
        }
    }
}

// ---------------- Kernel 3: merge the four splits ----------------
__global__ __launch_bounds__(256) void merge(float* __restrict__ o0,
                                             const _Float16* __restrict__ op,
                                             const float2* __restrict__ stats) {
    int idx = blockIdx.x * 256 + threadIdx.x;   // 524288 float4-granules
    int row = idx >> 4;
    int c = (idx & 15) << 2;
    float2 s0 = stats[row];
    float2 s1 = stats[NROWS + row];
    float2 s2 = stats[2 * NROWS + row];
    float2 s3 = stats[3 * NROWS + row];
    float m = fmaxf(fmaxf(s0.x, s1.x), fmaxf(s2.x, s3.x));
    float w0 = __builtin_amdgcn_exp2f(s0.x - m);
    float w1 = __builtin_amdgcn_exp2f(s1.x - m);
    float w2 = __builtin_amdgcn_exp2f(s2.x - m);
    float w3 = __builtin_amdgcn_exp2f(s3.x - m);
    float inv = 1.0f / (w0 * s0.y + w1 * s1.y + w2 * s2.y + w3 * s3.y);
    long off = (long)row * 64 + c;
    float4 a = *(const float4*)(o0 + off);
    f16x4 p1 = *(const f16x4*)(op + off);
    f16x4 p2 = *(const f16x4*)(op + 2097152 + off);
    f16x4 p3 = *(const f16x4*)(op + 4194304 + off);
    float4 o;
    o.x = (w0 * a.x + w1 * (float)p1[0] + w2 * (float)p2[0] + w3 * (float)p3[0]) * inv;
    o.y = (w0 * a.y + w1 * (float)p1[1] + w2 * (float)p2[1] + w3 * (float)p3[1]) * inv;
    o.z = (w0 * a.z + w1 * (float)p1[2] + w2 * (float)p2[2] + w3 * (float)p3[2]) * inv;
    o.w = (w0 * a.w + w1 * (float)p1[3] + w2 * (float)p2[3] + w3 * (float)p3[3]) * inv;
    *(float4*)(o0 + off) = o;
}

extern "C" void kernel_launch(void* const* d_in, const int* in_sizes, int n_in,
                              void* d_out, int out_size, void* d_ws, size_t ws_size,
                              hipStream_t stream) {
    const float* x  = (const float*)d_in[0];
    const float* Wq = (const float*)d_in[1];
    const float* bq = (const float*)d_in[2];
    const float* Wk = (const float*)d_in[3];
    const float* bk = (const float*)d_in[4];
    const float* Wv = (const float*)d_in[5];
    const float* bv = (const float*)d_in[6];
    float* out = (float*)d_out;

    char* wsb = (char*)d_ws;
    _Float16* wt = (_Float16*)wsb;                    // [0, 294912)
    _Float16* qb = (_Float16*)(wsb + 294912);         // 4 MB each
    _Float16* kb = qb + 2097152;
    _Float16* vb = kb + 2097152;
    _Float16* op = (_Float16*)(wsb + 12877824);       // 3 x 4 MB f16 partials
    float2* stats = (float2*)(wsb + 25460736);        // 1 MB

    prep_w<<<576, 256, 0, stream>>>(Wq, Wk, Wv, wt);
    qkv_proj<<<1536, 256, 0, stream>>>(x, wt, bq, bk, bv, qb, kb, vb);
    attn<<<2048, 256, 0, stream>>>(qb, kb, vb, out, op, stats);
    merge<<<2048, 256, 0, stream>>>(out, op, stats);
}

// Round 7
// 241.250 us; speedup vs baseline: 1.2793x; 1.2624x over previous
//
#include <hip/hip_runtime.h>

typedef _Float16 f16x8 __attribute__((ext_vector_type(8)));
typedef _Float16 f16x4 __attribute__((ext_vector_type(4)));
typedef float f32x4 __attribute__((ext_vector_type(4)));

#define NMAT3 (3 * 768 * 64)
#define NROWS 32768   // 8 * 4096

// ---------------- Kernel 0: W transpose/convert ----------------
// Wt layout: [n = mat*64 + d][k], f16.
__global__ __launch_bounds__(256) void prep_w(const float* __restrict__ Wq,
                                              const float* __restrict__ Wk,
                                              const float* __restrict__ Wv,
                                              _Float16* __restrict__ wt) {
    int tid = blockIdx.x * 256 + threadIdx.x;
    if (tid >= NMAT3) return;
    int m = tid / (768 * 64);
    int rem = tid - m * (768 * 64);
    int k = rem >> 6;
    int n = rem & 63;
    const float* W = (m == 0) ? Wq : (m == 1) ? Wk : Wv;
    float v = W[k * 64 + n];
    wt[(m * 64 + n) * 768 + k] = (_Float16)v;
}

// ---------------- Kernel 1: QKV projection, fully-coalesced staging -------
// 512 blocks x (64 rows x 192 cols), K-step 64, 4 waves.
// Every global load instruction is wave-contiguous (1KB, 8 lines) to avoid
// TA line-split serialization. wt staged via XOR-swizzled source permutation
// (linear LDS dest, same XOR on frag read). x staged fp32->f16 with padded
// LDS rows. T14: next step's loads issued during current compute.
__global__ __launch_bounds__(256) void qkv_proj(const float* __restrict__ x,
                                                const _Float16* __restrict__ wt,
                                                const float* __restrict__ bq,
                                                const float* __restrict__ bk,
                                                const float* __restrict__ bv,
                                                _Float16* __restrict__ qo,
                                                _Float16* __restrict__ ko,
                                                _Float16* __restrict__ vo) {
    __shared__ alignas(16) _Float16 xs[64][68];      // 64 rows x 64 k, pad->68
    __shared__ alignas(16) _Float16 wsh[192 * 64];   // flat, swizzled slots

    const int t = threadIdx.x;
    const int lane = t & 63;
    const int w = t >> 6;
    const int l15 = lane & 15;
    const int lg = lane >> 4;
    const int row0 = blockIdx.x * 64;

    f32x4 acc[12];
#pragma unroll
    for (int i = 0; i < 12; i++) acc[i] = (f32x4)(0.0f);

    // per-thread staging coords (constant across K-steps)
    // x: 4 passes, chunk c = p*256+t: row=c>>4, ch=c&15 (16B fp32 chunks)
    // wt: 6 passes, chunk c = p*256+t: n=c>>3, j=c&7 (16B f16 chunks);
    //     global k-chunk loaded = j ^ (n&7); LDS dest linear (byte c*16)
    float4 xr[4];
    f16x8 wr[6];

#pragma unroll
    for (int p = 0; p < 4; p++) {
        int c = p * 256 + t;
        int row = c >> 4, ch = c & 15;
        xr[p] = *(const float4*)(x + (long)(row0 + row) * 768 + ch * 4);
    }
#pragma unroll
    for (int p = 0; p < 6; p++) {
        int c = p * 256 + t;
        int n = c >> 3, j = c & 7;
        wr[p] = *(const f16x8*)(wt + (long)n * 768 + ((j ^ (n & 7)) * 8));
    }

    for (int step = 0; step < 12; step++) {
        __syncthreads();   // previous step's LDS reads complete
#pragma unroll
        for (int p = 0; p < 4; p++) {
            int c = p * 256 + t;
            int row = c >> 4, ch = c & 15;
            f16x4 h;
            h[0] = (_Float16)xr[p].x; h[1] = (_Float16)xr[p].y;
            h[2] = (_Float16)xr[p].z; h[3] = (_Float16)xr[p].w;
            *(f16x4*)(&xs[row][ch * 4]) = h;
        }
#pragma unroll
        for (int p = 0; p < 6; p++) {
            int c = p * 256 + t;
            *(f16x8*)(&wsh[c * 8]) = wr[p];
        }
        __syncthreads();   // tile ready

        if (step < 11) {   // T14: issue next step's loads now, write later
            const int k0n = (step + 1) * 64;
#pragma unroll
            for (int p = 0; p < 4; p++) {
                int c = p * 256 + t;
                int row = c >> 4, ch = c & 15;
                xr[p] = *(const float4*)(x + (long)(row0 + row) * 768 + k0n + ch * 4);
            }
#pragma unroll
            for (int p = 0; p < 6; p++) {
                int c = p * 256 + t;
                int n = c >> 3, j = c & 7;
                wr[p] = *(const f16x8*)(wt + (long)n * 768 + k0n + ((j ^ (n & 7)) * 8));
            }
        }

        // compute: wave = 16 rows x 192 cols, K=64
        f16x8 af[2];
#pragma unroll
        for (int kk = 0; kk < 2; kk++)
            af[kk] = *(const f16x8*)(&xs[16 * w + l15][kk * 32 + lg * 8]);
#pragma unroll
        for (int nf = 0; nf < 12; nf++) {
            const int n = nf * 16 + l15;
#pragma unroll
            for (int kk = 0; kk < 2; kk++) {
                const int kap = (kk * 4 + lg) ^ (l15 & 7);
                f16x8 bfr = *(const f16x8*)(&wsh[n * 64 + kap * 8]);
                acc[nf] = __builtin_amdgcn_mfma_f32_16x16x32_f16(af[kk], bfr, acc[nf], 0, 0, 0);
            }
        }
    }

    _Float16* outs[3] = {qo, ko, vo};
    const float* biases[3] = {bq, bk, bv};
#pragma unroll
    for (int nf = 0; nf < 12; nf++) {
        const int mat = nf >> 2;
        const int dcol = (nf & 3) * 16 + l15;
        const float bias = biases[mat][dcol];
#pragma unroll
        for (int r = 0; r < 4; r++) {
            int grow = row0 + 16 * w + lg * 4 + r;
            outs[mat][(long)grow * 64 + dcol] = (_Float16)(acc[nf][r] + bias);
        }
    }
}

// ---------------- Kernel 2: causal flash attention, s-split 4-way ---------
// (unchanged from R6 — passed, ~sub-110us)
__global__ __launch_bounds__(256) void attn(const _Float16* __restrict__ qg,
                                            const _Float16* __restrict__ kg,
                                            const _Float16* __restrict__ vg,
                                            float* __restrict__ o0,
                                            _Float16* __restrict__ op,
                                            float2* __restrict__ stats) {
    __shared__ alignas(16) _Float16 Ks[64][72];
    __shared__ alignas(16) _Float16 Vs[64][72];     // [d][s] transposed
    __shared__ alignas(16) _Float16 Ps[4][16][72];

    const int t = threadIdx.x;
    const int lane = t & 63;
    const int w = t >> 6;
    const int l15 = lane & 15;
    const int lg = lane >> 4;

    const int bid = blockIdx.x;
    const int b = bid & 7;
    const int rest = bid >> 3;
    const int h = rest & 3;
    const int tq = rest >> 2;
    const int qt = 63 - tq;          // LPT: heavy tiles first

    const int qbase = qt * 64;
    const long rowb = (long)b * 4096;
    const int ntiles = qt + 1;
    const int base = ntiles >> 2;
    const int rem = ntiles & 3;
    const int cnt = base + (h < rem ? 1 : 0);
    const int t0 = h * base + (h < rem ? h : rem);

    float mrow[4], lrow[4];
#pragma unroll
    for (int r = 0; r < 4; r++) { mrow[r] = -1e30f; lrow[r] = 0.0f; }

    if (cnt > 0) {
        const int sK = lane;
        const int dK = w * 16;

        f16x8 qf[2];
        {
            const _Float16* qptr = qg + (rowb + qbase + 16 * w + l15) * 64 + lg * 8;
            qf[0] = *(const f16x8*)(qptr);
            qf[1] = *(const f16x8*)(qptr + 32);
        }

        f32x4 oacc[4];
#pragma unroll
        for (int i = 0; i < 4; i++) oacc[i] = (f32x4)(0.0f);

        const float kscale = 0.125f * 1.44269504088896340736f;

        f16x8 krg0, krg1, vrg0, vrg1;
        {
            const long nb = rowb + (long)t0 * 64 + sK;
            const _Float16* ksrc = kg + nb * 64 + dK;
            krg0 = *(const f16x8*)(ksrc);
            krg1 = *(const f16x8*)(ksrc + 8);
            const _Float16* vsrc = vg + nb * 64 + dK;
            vrg0 = *(const f16x8*)(vsrc);
            vrg1 = *(const f16x8*)(vsrc + 8);
            *(f16x8*)(&Ks[sK][dK]) = krg0;
            *(f16x8*)(&Ks[sK][dK + 8]) = krg1;
#pragma unroll
            for (int j = 0; j < 8; j++) Vs[dK + j][sK] = vrg0[j];
#pragma unroll
            for (int j = 0; j < 8; j++) Vs[dK + 8 + j][sK] = vrg1[j];
        }

        for (int i = 0; i < cnt; i++) {
            const int st = t0 + i;
            const int sbase = st * 64;
            __syncthreads();

            if (i + 1 < cnt) {
                const long nb = rowb + sbase + 64 + sK;
                const _Float16* ksrc = kg + nb * 64 + dK;
                krg0 = *(const f16x8*)(ksrc);
                krg1 = *(const f16x8*)(ksrc + 8);
                const _Float16* vsrc = vg + nb * 64 + dK;
                vrg0 = *(const f16x8*)(vsrc);
                vrg1 = *(const f16x8*)(vsrc + 8);
            }

            f32x4 sacc[4];
            __builtin_amdgcn_s_setprio(1);
#pragma unroll
            for (int cf = 0; cf < 4; cf++) {
                sacc[cf] = (f32x4)(0.0f);
#pragma unroll
                for (int kk = 0; kk < 2; kk++) {
                    f16x8 bfrag = *(const f16x8*)(&Ks[16 * cf + l15][kk * 32 + lg * 8]);
                    sacc[cf] = __builtin_amdgcn_mfma_f32_16x16x32_f16(qf[kk], bfrag, sacc[cf], 0, 0, 0);
                }
            }
            __builtin_amdgcn_s_setprio(0);

            const bool diag = (st == qt);
            float sv[4][4];
#pragma unroll
            for (int cf = 0; cf < 4; cf++) {
                int scol = sbase + 16 * cf + l15;
#pragma unroll
                for (int r = 0; r < 4; r++) {
                    float val = sacc[cf][r] * kscale;
                    if (diag) {
                        int qrow = qbase + 16 * w + lg * 4 + r;
                        if (scol > qrow) val = -1e30f;
                    }
                    sv[cf][r] = val;
                }
            }

            float fr[4];
#pragma unroll
            for (int r = 0; r < 4; r++) {
                float mx = fmaxf(fmaxf(sv[0][r], sv[1][r]), fmaxf(sv[2][r], sv[3][r]));
                mx = fmaxf(mx, __shfl_xor(mx, 1, 64));
                mx = fmaxf(mx, __shfl_xor(mx, 2, 64));
                mx = fmaxf(mx, __shfl_xor(mx, 4, 64));
                mx = fmaxf(mx, __shfl_xor(mx, 8, 64));
                float mnew = fmaxf(mrow[r], mx);
                fr[r] = __builtin_amdgcn_exp2f(mrow[r] - mnew);
                mrow[r] = mnew;
                float psum = 0.0f;
#pragma unroll
                for (int cf = 0; cf < 4; cf++) {
                    float p = __builtin_amdgcn_exp2f(sv[cf][r] - mnew);
                    sv[cf][r] = p;
                    psum += p;
                }
                psum += __shfl_xor(psum, 1, 64);
                psum += __shfl_xor(psum, 2, 64);
                psum += __shfl_xor(psum, 4, 64);
                psum += __shfl_xor(psum, 8, 64);
                lrow[r] = lrow[r] * fr[r] + psum;
            }
#pragma unroll
            for (int df = 0; df < 4; df++)
#pragma unroll
                for (int r = 0; r < 4; r++) oacc[df][r] *= fr[r];

#pragma unroll
            for (int cf = 0; cf < 4; cf++)
#pragma unroll
                for (int r = 0; r < 4; r++)
                    Ps[w][lg * 4 + r][16 * cf + l15] = (_Float16)sv[cf][r];

            __builtin_amdgcn_s_setprio(1);
#pragma unroll
            for (int kk = 0; kk < 2; kk++) {
                f16x8 pfrag = *(const f16x8*)(&Ps[w][l15][kk * 32 + lg * 8]);
#pragma unroll
                for (int df = 0; df < 4; df++) {
                    f16x8 vfrag = *(const f16x8*)(&Vs[16 * df + l15][kk * 32 + lg * 8]);
                    oacc[df] = __builtin_amdgcn_mfma_f32_16x16x32_f16(pfrag, vfrag, oacc[df], 0, 0, 0);
                }
            }
            __builtin_amdgcn_s_setprio(0);

            __syncthreads();
            if (i + 1 < cnt) {
                *(f16x8*)(&Ks[sK][dK]) = krg0;
                *(f16x8*)(&Ks[sK][dK + 8]) = krg1;
#pragma unroll
                for (int j = 0; j < 8; j++) Vs[dK + j][sK] = vrg0[j];
#pragma unroll
                for (int j = 0; j < 8; j++) Vs[dK + 8 + j][sK] = vrg1[j];
            }
        }

        if (h == 0) {
#pragma unroll
            for (int df = 0; df < 4; df++)
#pragma unroll
                for (int r = 0; r < 4; r++) {
                    int qrow = qbase + 16 * w + lg * 4 + r;
                    o0[(rowb + qrow) * 64 + 16 * df + l15] = oacc[df][r];
                }
        } else {
            _Float16* opart = op + (long)(h - 1) * 2097152;
#pragma unroll
            for (int df = 0; df < 4; df++)
#pragma unroll
                for (int r = 0; r < 4; r++) {
                    int qrow = qbase + 16 * w + lg * 4 + r;
                    opart[(rowb + qrow) * 64 + 16 * df + l15] = (_Float16)oacc[df][r];
                }
        }
    }

    if (l15 == 0) {
#pragma unroll
        for (int r = 0; r < 4; r++) {
            long row = rowb + qbase + 16 * w + lg * 4 + r;
            stats[(long)h * NROWS + row] = make_float2(mrow[r], lrow[r]);
        }
    }
}

// ---------------- Kernel 3: merge the four splits ----------------
__global__ __launch_bounds__(256) void merge(float* __restrict__ o0,
                                             const _Float16* __restrict__ op,
                                             const float2* __restrict__ stats) {
    int idx = blockIdx.x * 256 + threadIdx.x;
    int row = idx >> 4;
    int c = (idx & 15) << 2;
    float2 s0 = stats[row];
    float2 s1 = stats[NROWS + row];
    float2 s2 = stats[2 * NROWS + row];
    float2 s3 = stats[3 * NROWS + row];
    float m = fmaxf(fmaxf(s0.x, s1.x), fmaxf(s2.x, s3.x));
    float w0 = __builtin_amdgcn_exp2f(s0.x - m);
    float w1 = __builtin_amdgcn_exp2f(s1.x - m);
    float w2 = __builtin_amdgcn_exp2f(s2.x - m);
    float w3 = __builtin_amdgcn_exp2f(s3.x - m);
    float inv = 1.0f / (w0 * s0.y + w1 * s1.y + w2 * s2.y + w3 * s3.y);
    long off = (long)row * 64 + c;
    float4 a = *(const float4*)(o0 + off);
    f16x4 p1 = *(const f16x4*)(op + off);
    f16x4 p2 = *(const f16x4*)(op + 2097152 + off);
    f16x4 p3 = *(const f16x4*)(op + 4194304 + off);
    float4 o;
    o.x = (w0 * a.x + w1 * (float)p1[0] + w2 * (float)p2[0] + w3 * (float)p3[0]) * inv;
    o.y = (w0 * a.y + w1 * (float)p1[1] + w2 * (float)p2[1] + w3 * (float)p3[1]) * inv;
    o.z = (w0 * a.z + w1 * (float)p1[2] + w2 * (float)p2[2] + w3 * (float)p3[2]) * inv;
    o.w = (w0 * a.w + w1 * (float)p1[3] + w2 * (float)p2[3] + w3 * (float)p3[3]) * inv;
    *(float4*)(o0 + off) = o;
}

extern "C" void kernel_launch(void* const* d_in, const int* in_sizes, int n_in,
                              void* d_out, int out_size, void* d_ws, size_t ws_size,
                              hipStream_t stream) {
    const float* x  = (const float*)d_in[0];
    const float* Wq = (const float*)d_in[1];
    const float* bq = (const float*)d_in[2];
    const float* Wk = (const float*)d_in[3];
    const float* bk = (const float*)d_in[4];
    const float* Wv = (const float*)d_in[5];
    const float* bv = (const float*)d_in[6];
    float* out = (float*)d_out;

    char* wsb = (char*)d_ws;
    _Float16* wt = (_Float16*)wsb;                    // [0, 294912)
    _Float16* qb = (_Float16*)(wsb + 294912);         // 4 MB each
    _Float16* kb = qb + 2097152;
    _Float16* vb = kb + 2097152;
    _Float16* op = (_Float16*)(wsb + 12877824);       // 3 x 4 MB f16 partials
    float2* stats = (float2*)(wsb + 25460736);        // 1 MB

    prep_w<<<576, 256, 0, stream>>>(Wq, Wk, Wv, wt);
    qkv_proj<<<512, 256, 0, stream>>>(x, wt, bq, bk, bv, qb, kb, vb);
    attn<<<2048, 256, 0, stream>>>(qb, kb, vb, out, op, stats);
    merge<<<2048, 256, 0, stream>>>(out, op, stats);
}